// Round 1
// baseline (364.135 us; speedup 1.0000x reference)
//
#include <hip/hip_runtime.h>
#include <math.h>

#define CLS 1000          // number of classes
#define VEC_PER_ROW 250   // 1000 / 4 float4s per row
#define BETA 3.0f
#define NPART 256         // partial sums for final reduction

// ---------------------------------------------------------------------------
// Kernel 0: cm_init — replaces the SDMA hipMemcpyAsync node.
//  - copies cost_matrix -> cm (vectorized, wave per row)
//  - computes inRowsum[t] = sum_p cost_matrix[t,p]  (row sums of the INPUT)
//  - zeroes tcount[] and the arrival counter (workspace is poisoned per iter)
// rowsum_final[t] = inRowsum[t] + #targets==t, so row_scale is redundant.
// ---------------------------------------------------------------------------
__global__ __launch_bounds__(256) void cm_init(
    const float* __restrict__ cm0,
    float* __restrict__ cm,
    float* __restrict__ inRowsum,
    int* __restrict__ tcount,
    int* __restrict__ counter)
{
    if (blockIdx.x == 0) {
        for (int i = threadIdx.x; i < CLS; i += 256) tcount[i] = 0;
        if (threadIdx.x == 0) *counter = 0;
    }
    const int wave = threadIdx.x >> 6;
    const int lane = threadIdx.x & 63;
    const int row  = blockIdx.x * 4 + wave;
    if (row >= CLS) return;

    const float4* src = (const float4*)(cm0 + (size_t)row * CLS);
    float4*       dst = (float4*)(cm  + (size_t)row * CLS);
    float s = 0.0f;
    for (int j = lane; j < VEC_PER_ROW; j += 64) {
        const float4 v = src[j];
        dst[j] = v;
        s += v.x + v.y + v.z + v.w;
    }
#pragma unroll
    for (int off = 32; off; off >>= 1) s += __shfl_xor(s, off);
    if (lane == 0) inRowsum[row] = s;
}

// ---------------------------------------------------------------------------
// Kernel A: one wave (64 lanes) per row, 4 rows per 256-thread block.
// Unchanged hot loop; lane 0 additionally bumps the target histogram
// (integer-exact in int, order-independent => determinism preserved).
// ---------------------------------------------------------------------------
__global__ __launch_bounds__(256) void softmax_pass(
    const float* __restrict__ outputs,
    const int* __restrict__ targets,
    float* __restrict__ cm,          // [CLS, CLS]
    int* __restrict__ tcount,        // [CLS]
    float* __restrict__ logp,        // [B]
    int* __restrict__ pred,          // [B]
    int B)
{
    const int wave = threadIdx.x >> 6;
    const int lane = threadIdx.x & 63;
    const int row  = blockIdx.x * 4 + wave;
    if (row >= B) return;

    const float4* rp = (const float4*)(outputs + (size_t)row * CLS);

    float4 r[4];
#pragma unroll
    for (int k = 0; k < 4; ++k) {
        const int j = lane + 64 * k;
        if (j < VEC_PER_ROW) {
            r[k] = rp[j];
        } else {
            r[k] = make_float4(-INFINITY, -INFINITY, -INFINITY, -INFINITY);
        }
    }

    // pass 1: max only (fmax tree -> v_max3 friendly)
    float m = -INFINITY;
#pragma unroll
    for (int k = 0; k < 4; ++k)
        m = fmaxf(m, fmaxf(fmaxf(r[k].x, r[k].y), fmaxf(r[k].z, r[k].w)));
#pragma unroll
    for (int off = 32; off; off >>= 1)
        m = fmaxf(m, __shfl_xor(m, off));

    // pass 2: exp-sum + equality argmax (min idx where x == m)
    float S  = 0.0f;
    int  idx = 0x7fffffff;
#pragma unroll
    for (int k = 0; k < 4; ++k) {
        const int base = (lane + 64 * k) * 4;
        const float* f = (const float*)&r[k];
#pragma unroll
        for (int c = 0; c < 4; ++c) {
            const float x = f[c];
            S += __expf(x - m);                    // tail: exp(-inf) = 0
            if (x == m) idx = min(idx, base + c);  // tail: -inf != m
        }
    }
#pragma unroll
    for (int off = 32; off; off >>= 1) {
        S   += __shfl_xor(S, off);
        idx  = min(idx, __shfl_xor(idx, off));
    }

    if (lane == 0) {
        const int t   = targets[row];
        const float xt = outputs[(size_t)row * CLS + t];  // L2-hot gather
        logp[row] = xt - m - __logf(S);
        pred[row] = idx;
        atomicAdd(&cm[(size_t)t * CLS + idx], 1.0f);
        atomicAdd(&tcount[t], 1);
    }
}

// ---------------------------------------------------------------------------
// Kernel B: fused finalize. Same grid-stride product loop as the old C1
// (bitwise-identical partials; scale computed inline from the algebraic
// row-sum identity), then last-arriving block replays old C2's exact
// butterfly over the NPART partials and writes -sum/B.
// Cross-XCD visibility: agent-scope release store of partial + acq_rel
// arrival counter + agent-scope acquire loads in the last block.
// ---------------------------------------------------------------------------
__global__ __launch_bounds__(256) void finalize(
    const float* __restrict__ cm,
    const float* __restrict__ inRowsum,
    const int* __restrict__ tcount,
    const float* __restrict__ logp,
    const int* __restrict__ pred,
    const int* __restrict__ targets,
    float* __restrict__ partial,     // [NPART]
    int* __restrict__ counter,
    float* __restrict__ out,
    int B)
{
    float v = 0.0f;
    for (int i = blockIdx.x * 256 + threadIdx.x; i < B; i += NPART * 256) {
        const int t = targets[i];
        const int p = pred[i];
        const float rs = inRowsum[t] + (float)tcount[t];     // == old rowsum
        v += logp[i] * cm[(size_t)t * CLS + p] * (BETA / fmaxf(1.0f, rs));
    }
    const int lane = threadIdx.x & 63;
    const int wave = threadIdx.x >> 6;
#pragma unroll
    for (int off = 32; off; off >>= 1) v += __shfl_xor(v, off);

    __shared__ float ssum[4];
    __shared__ int lastFlag;
    if (lane == 0) ssum[wave] = v;
    __syncthreads();
    if (threadIdx.x == 0) {
        const float p4 = ssum[0] + ssum[1] + ssum[2] + ssum[3];
        __hip_atomic_store(&partial[blockIdx.x], p4,
                           __ATOMIC_RELEASE, __HIP_MEMORY_SCOPE_AGENT);
        const int old = __hip_atomic_fetch_add(counter, 1,
                           __ATOMIC_ACQ_REL, __HIP_MEMORY_SCOPE_AGENT);
        lastFlag = (old == NPART - 1);
    }
    __syncthreads();
    if (!lastFlag) return;

    // last block: reduce NPART partials exactly like the old finalize_reduce
    float w = (threadIdx.x < NPART)
        ? __hip_atomic_load(&partial[threadIdx.x],
                            __ATOMIC_ACQUIRE, __HIP_MEMORY_SCOPE_AGENT)
        : 0.0f;
#pragma unroll
    for (int off = 32; off; off >>= 1) w += __shfl_xor(w, off);
    __syncthreads();                       // ssum reuse
    if (lane == 0) ssum[wave] = w;
    __syncthreads();
    if (threadIdx.x == 0)
        out[0] = -(ssum[0] + ssum[1] + ssum[2] + ssum[3]) / (float)B;
}

extern "C" void kernel_launch(void* const* d_in, const int* in_sizes, int n_in,
                              void* d_out, int out_size, void* d_ws, size_t ws_size,
                              hipStream_t stream)
{
    const float* outputs     = (const float*)d_in[0];
    const int*   targets     = (const int*)d_in[1];
    const float* cost_matrix = (const float*)d_in[2];
    const int B = in_sizes[1];

    // workspace layout (16B aligned)
    char* ws = (char*)d_ws;
    float* cm       = (float*)(ws);                               // 4,000,000 B
    float* logp     = (float*)(ws + 4000000);                     // B*4
    int*   pred     = (int*)  (ws + 4000000 + (size_t)B * 4);     // B*4
    float* inRowsum = (float*)(ws + 4000000 + (size_t)B * 8);            // 4096
    int*   tcount   = (int*)  (ws + 4000000 + (size_t)B * 8 + 4096);     // 4096
    float* partial  = (float*)(ws + 4000000 + (size_t)B * 8 + 8192);     // 1024
    int*   counter  = (int*)  (ws + 4000000 + (size_t)B * 8 + 9216);     // 4

    cm_init<<<(CLS + 3) / 4, 256, 0, stream>>>(cost_matrix, cm, inRowsum,
                                               tcount, counter);
    softmax_pass<<<(B + 3) / 4, 256, 0, stream>>>(outputs, targets, cm, tcount,
                                                  logp, pred, B);
    finalize<<<NPART, 256, 0, stream>>>(cm, inRowsum, tcount, logp, pred,
                                        targets, partial, counter,
                                        (float*)d_out, B);
}